// Round 12
// baseline (417.550 us; speedup 1.0000x reference)
//
#include <hip/hip_runtime.h>

// SparseConv2d N=32, OC=IC=256, H=W=56, K=3, pad=1 -> dense bf16 MFMA implicit GEMM
// V9: stage-once / free-run. V3..V8 all 165-205us @ 23-30% MfmaUtil regardless of
//     VALU/conflicts/occupancy/A-locality -> the invariant is the 2-phase structure's
//     16 per-chunk barrier drains (m233: ~72% stall). Restructure: 512-thread block,
//     256oc x 224px (4-row strip), LDS holds 128 ic at once (89KB, 1 block/CU,
//     2 waves/SIMD). K = 2 chunks of 128ic -> 3 barriers/block total. After each
//     stage, waves FREE-RUN 36 (j,c8) steps (4 A-loads + 7 ds_reads + 28 MFMA) with
//     no sync; 2 waves/SIMD cover latencies (m114). acc[4][7]=112 AGPR, ~222 regs.
//     Swizzle slot=(c8*4+q)^(c&7), inverse on staging source (both-sides rule).
constexpr int NB=32, ICC=256, OCC=256, HH=56, WW=56;
constexpr int HW=HH*WW, CHW=ICC*HW;
constexpr int STRIPS=14;               // 4-row output strips
constexpr int CELLB=256;               // 128 ic * 2B per (row,col) cell
constexpr int ROWB2=58*CELLB;          // 14848 B per LDS row
constexpr int XTB=6*ROWB2;             // 89088 B total LDS
// ---- legacy fp32 path constants (fallback if ws too small) ----
constexpr int YT=14;
constexpr int LROW=58;
constexpr int PAD=36;
constexpr int LDS_ELEMS=6*LROW*PAD;

using short8  = __attribute__((ext_vector_type(8))) short;   // 8 x bf16 bits (A/B frag)
using short4v = __attribute__((ext_vector_type(4))) short;
using f32x4   = __attribute__((ext_vector_type(4))) float;   // C/D frag

__device__ inline unsigned bf16rne(float x){
  unsigned u = __float_as_uint(x);
  return (u + 0x7fffu + ((u>>16)&1u)) >> 16;   // round-to-nearest-even
}

// wb[j][oc][ic] bf16, j = kh*3+kw, masked weights. 1.18 MB in d_ws.
__global__ __launch_bounds__(256) void pack_weights(
    const float* __restrict__ w, const int* __restrict__ mask,
    unsigned short* __restrict__ wb){
  const int oc = blockIdx.x, ic = threadIdx.x;
  const int base = (oc*ICC + ic)*9;
  #pragma unroll
  for (int j=0;j<9;++j){
    float v = (mask[base+j] != 0) ? w[base+j] : 0.f;
    wb[(j*OCC + oc)*ICC + ic] = (unsigned short)bf16rne(v);
  }
}

// in[n][ic][y][x] fp32 -> inb[n][y][x][ic] bf16 (channels-last). One block per (n,y) row.
// Paired ic-planes -> u32 LDS writes (half the DS ops).
__global__ __launch_bounds__(256) void pack_input(
    const float* __restrict__ in, unsigned short* __restrict__ inb){
  __shared__ unsigned t2[56*130];            // [x][128 icp + 2 pad] u32
  const int bid = blockIdx.x;
  const int n = bid/56, y = bid - n*56;
  const float* src = in + (size_t)n*CHW + y*WW;
  const int tid = threadIdx.x;
  #pragma unroll
  for (int i=0;i<7;++i){                     // 1792 items: (icp 0..127, xg 0..13)
    int idx = tid + i*256;
    int icp = idx / 14, xg = idx - icp*14;
    const float* gp = src + (2*icp)*HW + xg*4;
    float4 g0 = *(const float4*)gp;          // ic plane 2*icp
    float4 g1 = *(const float4*)(gp + HW);   // ic plane 2*icp+1
    int xb = xg*4;
    t2[(xb+0)*130 + icp] = bf16rne(g0.x) | (bf16rne(g1.x)<<16);
    t2[(xb+1)*130 + icp] = bf16rne(g0.y) | (bf16rne(g1.y)<<16);
    t2[(xb+2)*130 + icp] = bf16rne(g0.z) | (bf16rne(g1.z)<<16);
    t2[(xb+3)*130 + icp] = bf16rne(g0.w) | (bf16rne(g1.w)<<16);
  }
  __syncthreads();
  unsigned* dst = (unsigned*)(inb + (size_t)(n*56+y)*56*256);
  #pragma unroll
  for (int i=0;i<28;++i){                    // 7168 u32, fully coalesced out
    int idx = tid + i*256;
    int x = idx >> 7, icp = idx & 127;
    dst[idx] = t2[x*130 + icp];
  }
}

__global__ __launch_bounds__(512,2) void conv_mfma(
    const unsigned short* __restrict__ inb, const unsigned short* __restrict__ wb,
    const float* __restrict__ bias, float* __restrict__ out){
  __shared__ __align__(16) unsigned short xt[XTB/2];   // [6 rows][58 cols][16 slots x 16B]

  // XCD-aware decode: lid&7 = XCD residue; 56 slots per residue = 4 ngrp x 14 strips
  const int lid  = blockIdx.x;
  const int xcd  = lid & 7, slot = lid >> 3;
  const int ngrp = slot / STRIPS, strip = slot - ngrp*STRIPS;
  const int n    = xcd + 8*ngrp;
  const int y0   = strip*4;

  const int tid  = threadIdx.x;
  const int lane = tid & 63, wv = tid >> 6;           // 8 waves
  const int q    = lane >> 4, l16 = lane & 15;

  // wave tile: 64 ocs x 112 px; 8 waves = 4 oc-groups x 2 px-halves = 256oc x 224px
  const int ocw = (wv & 3)*64;
  const int pxw = (wv >> 2)*112;

  // per-(p,kw): cb = LDS byte addr of cell (row=yl, col=c) at kh=0; xm = c&7 (swizzle key)
  int cb[7][3], xm[7][3];
  #pragma unroll
  for (int p=0;p<7;++p){
    int px = pxw + p*16 + l16;          // pixel within 4x56 strip (row-crossing OK)
    int yl = px / 56, x = px - yl*56;
    #pragma unroll
    for (int kw=0;kw<3;++kw){
      int c = x + kw;                   // LDS col (col c holds image x=c-1)
      cb[p][kw] = yl*ROWB2 + c*CELLB;
      xm[p][kw] = c & 7;
    }
  }

  f32x4 acc[4][7];
  #pragma unroll
  for (int s=0;s<4;++s)
    #pragma unroll
    for (int p=0;p<7;++p) acc[s][p] = (f32x4){0.f,0.f,0.f,0.f};

  const int rskipA = (strip==0)         ? 0 : -1;   // input row y0-1 invalid -> zero
  const int rskipB = (strip==STRIPS-1)  ? 5 : -1;   // input row y0+4 invalid -> zero

  const unsigned short* nb = inb + (size_t)n*(56*56*256);

  // ---- one-time zero of halo cells (disjoint from staged cells, no extra barrier) ----
  const f32x4 z4 = (f32x4){0.f,0.f,0.f,0.f};
  if (tid < 192){                       // halo cols c=0,57: 6 rows x 2 x 256B
    int row = tid/32, t2 = tid & 31, cs = t2>>4, i16 = t2 & 15;
    *(f32x4*)((char*)xt + row*ROWB2 + cs*57*CELLB + i16*16) = z4;
  }
  if (strip==0)        for (int i=tid;i<ROWB2/16;i+=512) *(f32x4*)((char*)xt + i*16) = z4;
  if (strip==STRIPS-1) for (int i=tid;i<ROWB2/16;i+=512) *(f32x4*)((char*)xt + 5*ROWB2 + i*16) = z4;

  // ---- stage 128-ic chunk (ic0 in {0,128}): 5376 x 16B global_load_lds ----
  // idx -> r=idx/896 (wave-uniform), c_in=(idx%896)>>4, s=idx&15.
  // dest = idx*16 + r*512 + 256 (lane-linear). Source swizzle: ic-group = s ^ (c&7).
  auto stage = [&](int ic0){
    #pragma unroll
    for (int i=0;i<11;++i){
      int idx = tid + i*512;
      if (idx < 5376){                        // i==10 -> tid<256, wave-granular
        int r = idx / 896;                    // wave-uniform (896 = 14*64)
        if (r != rskipA && r != rskipB){
          int rm = idx - r*896;
          int c_in = rm >> 4, s = rm & 15;
          int y = y0 - 1 + r;
          int g = s ^ ((1 + c_in) & 7);       // inverse swizzle on global source
          const unsigned short* gp = nb + (y*56 + c_in)*256 + ic0 + g*8;
          char* lp = (char*)xt + idx*16 + r*512 + 256;
          __builtin_amdgcn_global_load_lds(
              (const __attribute__((address_space(1))) void*)gp,
              (__attribute__((address_space(3))) void*)lp, 16, 0, 0);
        }
      }
    }
  };

  // ---- free-run compute over resident 128 ic: 9 j x 4 c8 steps, NO barriers ----
  auto compute = [&](int ic0){
    #pragma unroll
    for (int j=0;j<9;++j){
      const int kh = j/3, kw = j - kh*3;
      const unsigned short* wj = wb + (j*OCC + ocw + l16)*ICC + ic0 + q*8;
      #pragma unroll
      for (int c8=0;c8<4;++c8){
        const unsigned short* wc = wj + c8*32;
        short8 a0 = *(const short8*)(wc          );
        short8 a1 = *(const short8*)(wc + 16*ICC );
        short8 a2 = *(const short8*)(wc + 32*ICC );
        short8 a3 = *(const short8*)(wc + 48*ICC );
        #pragma unroll
        for (int p=0;p<7;++p){
          int slt = ((c8<<2) | q) ^ xm[p][kw];
          short8 b = *(const short8*)((char*)xt + cb[p][kw] + kh*ROWB2 + (slt<<4));
          acc[0][p] = __builtin_amdgcn_mfma_f32_16x16x32_bf16(a0, b, acc[0][p], 0,0,0);
          acc[1][p] = __builtin_amdgcn_mfma_f32_16x16x32_bf16(a1, b, acc[1][p], 0,0,0);
          acc[2][p] = __builtin_amdgcn_mfma_f32_16x16x32_bf16(a2, b, acc[2][p], 0,0,0);
          acc[3][p] = __builtin_amdgcn_mfma_f32_16x16x32_bf16(a3, b, acc[3][p], 0,0,0);
        }
      }
    }
  };

  // schedule: 3 barriers per block total
  stage(0);
  __syncthreads();            // drains stage vmcnt + halo ds_writes -> chunk0 ready
  compute(0);
  __syncthreads();            // all reads of chunk0 done before restage
  stage(128);
  __syncthreads();            // chunk1 ready
  compute(128);

  // ---- epilogue: D row = oc (quad*4+reg), col = px (lane&15)  [m89 layout] ----
  #pragma unroll
  for (int s=0;s<4;++s){
    const int oc4 = ocw + s*16 + q*4;
    float4 bv = *(const float4*)(bias + oc4);
    #pragma unroll
    for (int i=0;i<4;++i){
      const float bb = (i==0)?bv.x:(i==1)?bv.y:(i==2)?bv.z:bv.w;
      float* op = out + (n*OCC + oc4 + i)*HW + y0*WW + pxw + l16;
      #pragma unroll
      for (int p=0;p<7;++p){
        op[p*16] = acc[s][p][i] + bb;
      }
    }
  }
}

// ---------------- fallback: V1 fp32-staging path (ws too small) ----------------
__global__ __launch_bounds__(256,2) void conv_mfma_f32(
    const float* __restrict__ in, const unsigned short* __restrict__ wb,
    const float* __restrict__ bias, float* __restrict__ out){
  __shared__ unsigned short xt[LDS_ELEMS];

  const int lid  = blockIdx.x;
  const int xcd  = lid & 7, slot = lid >> 3;
  const int ngrp = slot / 28, rem = slot - ngrp*28;
  const int mt   = rem / 14,  yt  = rem - mt*14;
  const int n    = xcd + 8*ngrp;
  const int y0   = yt*4, ocb = mt*128;

  const int tid  = threadIdx.x;
  const int lane = tid & 63, wv = tid >> 6;
  const int q    = lane >> 4, l16 = lane & 15;

  for (int i = tid; i < LDS_ELEMS/2; i += 256) ((unsigned*)xt)[i] = 0u;

  const int ocw = ocb + (wv & 1)*64;
  const int pxw = (wv >> 1)*112;

  int pbase[7];
  #pragma unroll
  for (int p=0;p<7;++p){
    int px = pxw + p*16 + l16;
    int ylv = px / 56, x = px - ylv*56;
    pbase[p] = (ylv*LROW + x)*(PAD*2) + q*16;
  }

  f32x4 acc[4][7];
  #pragma unroll
  for (int s=0;s<4;++s)
    #pragma unroll
    for (int p=0;p<7;++p) acc[s][p] = (f32x4){0.f,0.f,0.f,0.f};

  const int rskipA = (yt==0)      ? 0 : -1;
  const int rskipB = (yt==YT-1)   ? 5 : -1;

  __syncthreads();

  for (int ch=0; ch<8; ++ch){
    const int ic0 = ch*32;
    #pragma unroll
    for (int i=0;i<6;++i){
      int idx = tid + i*256;
      if (idx < 1344){
        int r  = idx / 224;
        int r2 = idx - r*224;
        int xg = r2 >> 4, icp = r2 & 15;
        if (r != rskipA && r != rskipB){
          int y = y0 - 1 + r;
          const float* gp = in + n*CHW + (ic0 + icp*2)*HW + y*WW + xg*4;
          float4 g0 = *(const float4*)gp;
          float4 g1 = *(const float4*)(gp + HW);
          unsigned w0 = bf16rne(g0.x) | (bf16rne(g1.x)<<16);
          unsigned w1 = bf16rne(g0.y) | (bf16rne(g1.y)<<16);
          unsigned w2 = bf16rne(g0.z) | (bf16rne(g1.z)<<16);
          unsigned w3 = bf16rne(g0.w) | (bf16rne(g1.w)<<16);
          unsigned* dp = (unsigned*)xt + (r*LROW + 1 + xg*4)*(PAD/2) + icp;
          dp[0]         = w0;
          dp[PAD/2]     = w1;
          dp[PAD]       = w2;
          dp[3*(PAD/2)] = w3;
        }
      }
    }
    __syncthreads();

    #pragma unroll
    for (int kh=0;kh<3;++kh){
      #pragma unroll
      for (int kw=0;kw<3;++kw){
        const int j = kh*3 + kw;
        const unsigned short* wp = wb + (j*OCC + ocw + l16)*ICC + ic0 + q*8;
        short8 a0 = *(const short8*)(wp          );
        short8 a1 = *(const short8*)(wp + 16*ICC );
        short8 a2 = *(const short8*)(wp + 32*ICC );
        short8 a3 = *(const short8*)(wp + 48*ICC );
        const int doff = (kh*LROW + kw)*(PAD*2);
        #pragma unroll
        for (int p=0;p<7;++p){
          const char* bp = (const char*)xt + pbase[p] + doff;
          short4v blo = *(const short4v*)(bp    );
          short4v bhi = *(const short4v*)(bp + 8);
          short8 b = __builtin_shufflevector(blo, bhi, 0,1,2,3,4,5,6,7);
          acc[0][p] = __builtin_amdgcn_mfma_f32_16x16x32_bf16(a0, b, acc[0][p], 0,0,0);
          acc[1][p] = __builtin_amdgcn_mfma_f32_16x16x32_bf16(a1, b, acc[1][p], 0,0,0);
          acc[2][p] = __builtin_amdgcn_mfma_f32_16x16x32_bf16(a2, b, acc[2][p], 0,0,0);
          acc[3][p] = __builtin_amdgcn_mfma_f32_16x16x32_bf16(a3, b, acc[3][p], 0,0,0);
        }
      }
    }
    __syncthreads();
  }

  #pragma unroll
  for (int s=0;s<4;++s){
    const int oc4 = ocw + s*16 + q*4;
    float4 bv = *(const float4*)(bias + oc4);
    #pragma unroll
    for (int i=0;i<4;++i){
      const float bb = (i==0)?bv.x:(i==1)?bv.y:(i==2)?bv.z:bv.w;
      float* op = out + (n*OCC + oc4 + i)*HW + y0*WW + pxw + l16;
      #pragma unroll
      for (int p=0;p<7;++p){
        op[p*16] = acc[s][p][i] + bb;
      }
    }
  }
}

extern "C" void kernel_launch(void* const* d_in, const int* in_sizes, int n_in,
                              void* d_out, int out_size, void* d_ws, size_t ws_size,
                              hipStream_t stream) {
  const float* in   = (const float*)d_in[0];
  const float* w    = (const float*)d_in[1];
  const float* bias = (const float*)d_in[2];
  const int*   mask = (const int*)d_in[3];
  float*       out  = (float*)d_out;
  unsigned short* wb = (unsigned short*)d_ws;        // 9*256*256*2 B = 1.18 MB

  const size_t WB_BYTES  = (size_t)9*OCC*ICC*2;      // 1179648 (256B aligned)
  const size_t INB_BYTES = (size_t)NB*HH*WW*ICC*2;   // 51.4 MB

  pack_weights<<<OCC, 256, 0, stream>>>(w, mask, wb);
  if (ws_size >= WB_BYTES + INB_BYTES){
    unsigned short* inb = (unsigned short*)((char*)d_ws + WB_BYTES);
    pack_input<<<NB*HH, 256, 0, stream>>>(in, inb);                  // 1792 blocks
    conv_mfma<<<8*4*STRIPS, 512, 0, stream>>>(inb, wb, bias, out);   // 448 blocks
  } else {
    conv_mfma_f32<<<8*4*2*YT, 256, 0, stream>>>(in, wb, bias, out);  // proven V1 path
  }
}

// Round 13
// 359.962 us; speedup vs baseline: 1.1600x; 1.1600x over previous
//
#include <hip/hip_runtime.h>

// SparseConv2d N=32, OC=IC=256, H=W=56, K=3, pad=1 -> dense bf16 MFMA implicit GEMM
// V10: V6's conflict-free swizzle at V5's register cost. Cycle tally over V3..V9 shows
//      the B-feed LDS conflicts are the binding constraint (V5 8-way = 2-3x LDS time;
//      V6 fixed conflicts but 21-reg base2 spilled). Key insight: x jumps +16/-40 across
//      p (both = 0 mod 8) so (x>>1)&3 and x&1 are per-thread CONSTANTS -> swizzle key
//      per kw only: addr = B[p] + C[kw] + kh*3712 (10 regs, 1 v_add per read).
//      No A-rotation (L2/L1-hot, compiler hoists). Structure = proven V5: 896 blocks,
//      128oc x 224px block, acc[4][7], stage->compute->syncthreads, setprio.
//      pack_input: u32-paired LDS writes (V8 version, 2x fewer DS ops).
constexpr int NB=32, ICC=256, OCC=256, HH=56, WW=56;
constexpr int HW=HH*WW, CHW=ICC*HW;
constexpr int YT=14;
constexpr int BUFB = 6*58*64;          // bytes per LDS buffer: [6 rows][58 cols][32 ic]*2B = 22272
constexpr int ROWB = 58*64;            // 3712 B per LDS row
// ---- legacy fp32 path constants (fallback if ws too small) ----
constexpr int LROW=58;
constexpr int PAD=36;
constexpr int LDS_ELEMS=6*LROW*PAD;

using short8  = __attribute__((ext_vector_type(8))) short;   // 8 x bf16 bits (A/B frag)
using short4v = __attribute__((ext_vector_type(4))) short;
using f32x4   = __attribute__((ext_vector_type(4))) float;   // C/D frag

__device__ inline unsigned bf16rne(float x){
  unsigned u = __float_as_uint(x);
  return (u + 0x7fffu + ((u>>16)&1u)) >> 16;   // round-to-nearest-even
}

// wb[j][oc][ic] bf16, j = kh*3+kw, masked weights. 1.18 MB in d_ws.
__global__ __launch_bounds__(256) void pack_weights(
    const float* __restrict__ w, const int* __restrict__ mask,
    unsigned short* __restrict__ wb){
  const int oc = blockIdx.x, ic = threadIdx.x;
  const int base = (oc*ICC + ic)*9;
  #pragma unroll
  for (int j=0;j<9;++j){
    float v = (mask[base+j] != 0) ? w[base+j] : 0.f;
    wb[(j*OCC + oc)*ICC + ic] = (unsigned short)bf16rne(v);
  }
}

// in[n][ic][y][x] fp32 -> inb[n][y][x][ic] bf16 (channels-last). One block per (n,y) row.
// Paired ic-planes -> u32 LDS writes (half the DS ops of the u16 version).
__global__ __launch_bounds__(256) void pack_input(
    const float* __restrict__ in, unsigned short* __restrict__ inb){
  __shared__ unsigned t2[56*130];            // [x][128 icp + 2 pad] u32
  const int bid = blockIdx.x;
  const int n = bid/56, y = bid - n*56;
  const float* src = in + (size_t)n*CHW + y*WW;
  const int tid = threadIdx.x;
  #pragma unroll
  for (int i=0;i<7;++i){                     // 1792 items: (icp 0..127, xg 0..13)
    int idx = tid + i*256;
    int icp = idx / 14, xg = idx - icp*14;
    const float* gp = src + (2*icp)*HW + xg*4;
    float4 g0 = *(const float4*)gp;          // ic plane 2*icp
    float4 g1 = *(const float4*)(gp + HW);   // ic plane 2*icp+1
    int xb = xg*4;
    t2[(xb+0)*130 + icp] = bf16rne(g0.x) | (bf16rne(g1.x)<<16);
    t2[(xb+1)*130 + icp] = bf16rne(g0.y) | (bf16rne(g1.y)<<16);
    t2[(xb+2)*130 + icp] = bf16rne(g0.z) | (bf16rne(g1.z)<<16);
    t2[(xb+3)*130 + icp] = bf16rne(g0.w) | (bf16rne(g1.w)<<16);
  }
  __syncthreads();
  unsigned* dst = (unsigned*)(inb + (size_t)(n*56+y)*56*256);
  #pragma unroll
  for (int i=0;i<28;++i){                    // 7168 u32, fully coalesced out
    int idx = tid + i*256;
    int x = idx >> 7, icp = idx & 127;
    dst[idx] = t2[x*130 + icp];
  }
}

__global__ __launch_bounds__(256,2) void conv_mfma(
    const unsigned short* __restrict__ inb, const unsigned short* __restrict__ wb,
    const float* __restrict__ bias, float* __restrict__ out){
  __shared__ __align__(16) unsigned short xt[2*6*58*32];   // 44544 B (2 buffers)

  // XCD-aware decode: lid&7 = XCD residue -> each XCD sees only 4 of 32 batches
  const int lid  = blockIdx.x;
  const int xcd  = lid & 7, slot = lid >> 3;          // 112 slots per residue
  const int ngrp = slot / 28, rem = slot - ngrp*28;   // same-n blocks adjacent
  const int mt   = rem / 14,  yt  = rem - mt*14;
  const int n    = xcd + 8*ngrp;
  const int y0   = yt*4, ocb = mt*128;

  const int tid  = threadIdx.x;
  const int lane = tid & 63, wv = tid >> 6;
  const int q    = lane >> 4, l16 = lane & 15;

  // wave tile: 64 ocs x 112 px (4 x 7 MFMA tiles of 16x16)
  const int ocw = ocb + (wv & 1)*64;
  const int pxw = (wv >> 1)*112;

  // B[p]: cell base (row,col at kw=0) in bytes. C[kw]: col shift + swizzle slot, per-thread
  // constant across p because x jumps +16/-40 (both = 0 mod 8) -> (x>>1)&3, x&1 invariant.
  int B[7];
  #pragma unroll
  for (int p=0;p<7;++p){
    int px = pxw + p*16 + l16;          // pixel within 4x56 tile (row-crossing OK)
    int yl = px / 56, x = px - yl*56;
    B[p] = yl*ROWB + x*64;
  }
  int x0   = (pxw + l16) % 56;          // p=0 pixel x (keys invariant across p)
  int xh   = (x0 >> 1) & 3, xpar = x0 & 1;
  int C[3];
  C[0] =       ((q ^  xh           ) << 4);
  C[1] =  64 + ((q ^ ((xh+xpar)&3) ) << 4);
  C[2] = 128 + ((q ^ ((xh+1   )&3) ) << 4);

  f32x4 acc[4][7];
  #pragma unroll
  for (int s=0;s<4;++s)
    #pragma unroll
    for (int p=0;p<7;++p) acc[s][p] = (f32x4){0.f,0.f,0.f,0.f};

  const int rskipA = (yt==0)      ? 0 : -1;   // input row y0-1 invalid -> stays zero
  const int rskipB = (yt==YT-1)   ? 5 : -1;   // input row y0+4 invalid -> stays zero

  const unsigned short* nb = inb + (size_t)n*(56*56*256);

  // ---- stage chunk ch into buffer buf: 24 wave-instrs (6 rows x 4 1KB granules) ----
  // t = wv*6+i -> row = t>>2, k = t&3; lane item ir = k*64+lane (<224, k=3 half-wave).
  // LDS dest linear from (row*58+1)*64 (global_load_lds lane-linear rule); swizzle on
  // the GLOBAL source: slot sub at col c=1+cc reads ic-group sub ^ ((c>>1)&3).
  auto stage = [&](int buf, int ch){
    const int ic0 = ch*32;
    #pragma unroll
    for (int i=0;i<6;++i){
      int t   = wv*6 + i;
      int row = t >> 2, k = t & 3;
      if (row != rskipA && row != rskipB){   // wave-uniform skip
        int ir = k*64 + lane;                // idx within row (16B units)
        int cc = ir >> 2, sub = ir & 3;
        int icg = sub ^ (((cc+1)>>1)&3);     // inverse swizzle on source
        int y  = y0 - 1 + row;
        const unsigned short* gp = nb + (y*56 + cc)*256 + ic0 + icg*8;
        char* lp = (char*)xt + buf*BUFB + (row*58 + 1)*64 + ir*16;
        if (ir < 224)                        // masks lanes>=32 of k==3 only
          __builtin_amdgcn_global_load_lds(
              (const __attribute__((address_space(1))) void*)gp,
              (__attribute__((address_space(3))) void*)lp, 16, 0, 0);
      }
    }
  };

  // ---- K-slice MFMA over buffer buf: 9 offsets x 32 ics ----
  // Read addr = xb + B[p] + C[kw] + kh*3712: one v_add per read, conflict-free slots.
  auto compute = [&](int buf, int ch){
    const int ic0 = ch*32;
    const char* xb = (const char*)xt + buf*BUFB;
    __builtin_amdgcn_s_setprio(1);
    #pragma unroll
    for (int j=0;j<9;++j){
      const int kh = j/3, kw = j - kh*3;
      const unsigned short* wj = wb + (j*OCC + ocw + l16)*ICC + ic0 + q*8;
      short8 a0 = *(const short8*)(wj          );
      short8 a1 = *(const short8*)(wj + 16*ICC );
      short8 a2 = *(const short8*)(wj + 32*ICC );
      short8 a3 = *(const short8*)(wj + 48*ICC );
      const int doff = C[kw] + kh*ROWB;
      #pragma unroll
      for (int p=0;p<7;++p){
        short8 b = *(const short8*)(xb + B[p] + doff);   // ds_read_b128
        acc[0][p] = __builtin_amdgcn_mfma_f32_16x16x32_bf16(a0, b, acc[0][p], 0,0,0);
        acc[1][p] = __builtin_amdgcn_mfma_f32_16x16x32_bf16(a1, b, acc[1][p], 0,0,0);
        acc[2][p] = __builtin_amdgcn_mfma_f32_16x16x32_bf16(a2, b, acc[2][p], 0,0,0);
        acc[3][p] = __builtin_amdgcn_mfma_f32_16x16x32_bf16(a3, b, acc[3][p], 0,0,0);
      }
    }
    __builtin_amdgcn_s_setprio(0);
  };

  // zero entire LDS once (halo cols 0/57, edge rows persist as zero through all chunks)
  #pragma unroll 4
  for (int i = tid; i < 2*BUFB/16; i += 256) ((f32x4*)xt)[i] = (f32x4){0.f,0.f,0.f,0.f};
  __syncthreads();                    // ds_writes drained before async staging

  stage(0, 0);
  __syncthreads();                    // drains vmcnt -> buf0 ready

  // main loop: prefetch ch+1 fire-and-forget, compute ch, one barrier per chunk.
  for (int ch=0; ch<8; ++ch){
    if (ch < 7) stage((ch+1)&1, ch+1);
    compute(ch&1, ch);
    __syncthreads();                  // drains prefetch vmcnt + guards buf reuse
  }

  // ---- epilogue: D row = oc (quad*4+reg), col = px (lane&15)  [m89 layout] ----
  #pragma unroll
  for (int s=0;s<4;++s){
    const int oc4 = ocw + s*16 + q*4;
    float4 bv = *(const float4*)(bias + oc4);
    #pragma unroll
    for (int i=0;i<4;++i){
      const float bb = (i==0)?bv.x:(i==1)?bv.y:(i==2)?bv.z:bv.w;
      float* op = out + (n*OCC + oc4 + i)*HW + y0*WW + pxw + l16;
      #pragma unroll
      for (int p=0;p<7;++p){
        op[p*16] = acc[s][p][i] + bb;
      }
    }
  }
}

// ---------------- fallback: V1 fp32-staging path (ws too small) ----------------
__global__ __launch_bounds__(256,2) void conv_mfma_f32(
    const float* __restrict__ in, const unsigned short* __restrict__ wb,
    const float* __restrict__ bias, float* __restrict__ out){
  __shared__ unsigned short xt[LDS_ELEMS];

  const int lid  = blockIdx.x;
  const int xcd  = lid & 7, slot = lid >> 3;
  const int ngrp = slot / 28, rem = slot - ngrp*28;
  const int mt   = rem / 14,  yt  = rem - mt*14;
  const int n    = xcd + 8*ngrp;
  const int y0   = yt*4, ocb = mt*128;

  const int tid  = threadIdx.x;
  const int lane = tid & 63, wv = tid >> 6;
  const int q    = lane >> 4, l16 = lane & 15;

  for (int i = tid; i < LDS_ELEMS/2; i += 256) ((unsigned*)xt)[i] = 0u;

  const int ocw = ocb + (wv & 1)*64;
  const int pxw = (wv >> 1)*112;

  int pbase[7];
  #pragma unroll
  for (int p=0;p<7;++p){
    int px = pxw + p*16 + l16;
    int ylv = px / 56, x = px - ylv*56;
    pbase[p] = (ylv*LROW + x)*(PAD*2) + q*16;
  }

  f32x4 acc[4][7];
  #pragma unroll
  for (int s=0;s<4;++s)
    #pragma unroll
    for (int p=0;p<7;++p) acc[s][p] = (f32x4){0.f,0.f,0.f,0.f};

  const int rskipA = (yt==0)      ? 0 : -1;
  const int rskipB = (yt==YT-1)   ? 5 : -1;

  __syncthreads();

  for (int ch=0; ch<8; ++ch){
    const int ic0 = ch*32;
    #pragma unroll
    for (int i=0;i<6;++i){
      int idx = tid + i*256;
      if (idx < 1344){
        int r  = idx / 224;
        int r2 = idx - r*224;
        int xg = r2 >> 4, icp = r2 & 15;
        if (r != rskipA && r != rskipB){
          int y = y0 - 1 + r;
          const float* gp = in + n*CHW + (ic0 + icp*2)*HW + y*WW + xg*4;
          float4 g0 = *(const float4*)gp;
          float4 g1 = *(const float4*)(gp + HW);
          unsigned w0 = bf16rne(g0.x) | (bf16rne(g1.x)<<16);
          unsigned w1 = bf16rne(g0.y) | (bf16rne(g1.y)<<16);
          unsigned w2 = bf16rne(g0.z) | (bf16rne(g1.z)<<16);
          unsigned w3 = bf16rne(g0.w) | (bf16rne(g1.w)<<16);
          unsigned* dp = (unsigned*)xt + (r*LROW + 1 + xg*4)*(PAD/2) + icp;
          dp[0]         = w0;
          dp[PAD/2]     = w1;
          dp[PAD]       = w2;
          dp[3*(PAD/2)] = w3;
        }
      }
    }
    __syncthreads();

    #pragma unroll
    for (int kh=0;kh<3;++kh){
      #pragma unroll
      for (int kw=0;kw<3;++kw){
        const int j = kh*3 + kw;
        const unsigned short* wp = wb + (j*OCC + ocw + l16)*ICC + ic0 + q*8;
        short8 a0 = *(const short8*)(wp          );
        short8 a1 = *(const short8*)(wp + 16*ICC );
        short8 a2 = *(const short8*)(wp + 32*ICC );
        short8 a3 = *(const short8*)(wp + 48*ICC );
        const int doff = (kh*LROW + kw)*(PAD*2);
        #pragma unroll
        for (int p=0;p<7;++p){
          const char* bp = (const char*)xt + pbase[p] + doff;
          short4v blo = *(const short4v*)(bp    );
          short4v bhi = *(const short4v*)(bp + 8);
          short8 b = __builtin_shufflevector(blo, bhi, 0,1,2,3,4,5,6,7);
          acc[0][p] = __builtin_amdgcn_mfma_f32_16x16x32_bf16(a0, b, acc[0][p], 0,0,0);
          acc[1][p] = __builtin_amdgcn_mfma_f32_16x16x32_bf16(a1, b, acc[1][p], 0,0,0);
          acc[2][p] = __builtin_amdgcn_mfma_f32_16x16x32_bf16(a2, b, acc[2][p], 0,0,0);
          acc[3][p] = __builtin_amdgcn_mfma_f32_16x16x32_bf16(a3, b, acc[3][p], 0,0,0);
        }
      }
    }
    __syncthreads();
  }

  #pragma unroll
  for (int s=0;s<4;++s){
    const int oc4 = ocw + s*16 + q*4;
    float4 bv = *(const float4*)(bias + oc4);
    #pragma unroll
    for (int i=0;i<4;++i){
      const float bb = (i==0)?bv.x:(i==1)?bv.y:(i==2)?bv.z:bv.w;
      float* op = out + (n*OCC + oc4 + i)*HW + y0*WW + pxw + l16;
      #pragma unroll
      for (int p=0;p<7;++p){
        op[p*16] = acc[s][p][i] + bb;
      }
    }
  }
}

extern "C" void kernel_launch(void* const* d_in, const int* in_sizes, int n_in,
                              void* d_out, int out_size, void* d_ws, size_t ws_size,
                              hipStream_t stream) {
  const float* in   = (const float*)d_in[0];
  const float* w    = (const float*)d_in[1];
  const float* bias = (const float*)d_in[2];
  const int*   mask = (const int*)d_in[3];
  float*       out  = (float*)d_out;
  unsigned short* wb = (unsigned short*)d_ws;        // 9*256*256*2 B = 1.18 MB

  const size_t WB_BYTES  = (size_t)9*OCC*ICC*2;      // 1179648 (256B aligned)
  const size_t INB_BYTES = (size_t)NB*HH*WW*ICC*2;   // 51.4 MB

  pack_weights<<<OCC, 256, 0, stream>>>(w, mask, wb);
  if (ws_size >= WB_BYTES + INB_BYTES){
    unsigned short* inb = (unsigned short*)((char*)d_ws + WB_BYTES);
    pack_input<<<NB*HH, 256, 0, stream>>>(in, inb);                  // 1792 blocks
    conv_mfma<<<8*4*2*YT, 256, 0, stream>>>(inb, wb, bias, out);     // 896 blocks
  } else {
    conv_mfma_f32<<<8*4*2*YT, 256, 0, stream>>>(in, wb, bias, out);  // proven V1 path
  }
}